// Round 1
// baseline (11.314 us; speedup 1.0000x reference)
//
#include <hip/hip_runtime.h>

#define PAD_TOK 0
#define UNK_TOK 1
#define END_TOK 2

__global__ __launch_bounds__(256) void ti_loss_row_kernel(
    const float* __restrict__ logits,     // [B, L, V]
    const int*   __restrict__ fwd,        // [B, L]
    const int*   __restrict__ tgt,        // [B, L]
    const int*   __restrict__ seqlen,     // [B]
    const int*   __restrict__ inserted,   // [B]
    float*       __restrict__ ws,         // ws[0..B) = sent_loss*active, ws[B..2B) = active
    int L, int V)
{
    const int b = blockIdx.x;
    const int t = threadIdx.x;
    const int* frow = fwd + (size_t)b * L;
    const int* trow = tgt + (size_t)b * L;
    const float* lrow = logits + (size_t)b * L * V;

    // ---- find first PAD position in this row (L if none) ----
    int fp = L;
    for (int i = t; i < L; i += 256) {
        if (frow[i] == PAD_TOK && i < fp) fp = i;
    }
    #pragma unroll
    for (int off = 32; off > 0; off >>= 1) {
        int o = __shfl_down(fp, off);
        fp = (o < fp) ? o : fp;
    }
    __shared__ int   s_fp[4];
    __shared__ float s_sum[4];
    __shared__ float s_cnt[4];
    const int wid  = t >> 6;
    const int lane = t & 63;
    if (lane == 0) s_fp[wid] = fp;
    __syncthreads();
    fp = min(min(s_fp[0], s_fp[1]), min(s_fp[2], s_fp[3]));

    // ---- accumulate -log(p) over UNK positions strictly before first PAD ----
    float sum = 0.f;
    float cnt = 0.f;
    for (int i = t; i < L; i += 256) {
        if (i < fp && frow[i] == UNK_TOK) {
            const int pt = (i == 0) ? trow[L - 1] : trow[i - 1];  // roll(targets,1)
            const float p = lrow[(size_t)i * V + pt];
            sum -= logf(p);
            cnt += 1.f;
        }
    }
    #pragma unroll
    for (int off = 32; off > 0; off >>= 1) {
        sum += __shfl_down(sum, off);
        cnt += __shfl_down(cnt, off);
    }
    if (lane == 0) { s_sum[wid] = sum; s_cnt[wid] = cnt; }
    __syncthreads();

    if (t == 0) {
        const float S = s_sum[0] + s_sum[1] + s_sum[2] + s_sum[3];
        const float C = s_cnt[0] + s_cnt[1] + s_cnt[2] + s_cnt[3];
        float sent;
        if (C > 0.f) {
            sent = S / fmaxf(C, 1.f);
        } else {
            const int sl = seqlen[b];
            sent = -logf(lrow[(size_t)(sl + 2) * V + END_TOK]);
        }
        const float act = (inserted[b] < seqlen[b]) ? 1.f : 0.f;
        ws[b]                = sent * act;
        ws[gridDim.x + b]    = act;
    }
}

__global__ void ti_loss_final_kernel(const float* __restrict__ ws,
                                     float* __restrict__ out, int B)
{
    if (threadIdx.x == 0) {
        float s = 0.f, a = 0.f;
        for (int b = 0; b < B; ++b) { s += ws[b]; a += ws[B + b]; }
        out[0] = s / fmaxf(a, 1.f);
    }
}

extern "C" void kernel_launch(void* const* d_in, const int* in_sizes, int n_in,
                              void* d_out, int out_size, void* d_ws, size_t ws_size,
                              hipStream_t stream) {
    const float* logits   = (const float*)d_in[0];
    const int*   fwd      = (const int*)d_in[1];
    const int*   tgt      = (const int*)d_in[2];
    const int*   seqlen   = (const int*)d_in[3];
    const int*   inserted = (const int*)d_in[4];
    float* out = (float*)d_out;
    float* ws  = (float*)d_ws;

    const int B = in_sizes[3];              // 16
    const int L = in_sizes[1] / B;          // 512
    const int V = in_sizes[0] / (B * L);    // 32000

    ti_loss_row_kernel<<<B, 256, 0, stream>>>(logits, fwd, tgt, seqlen, inserted, ws, L, V);
    ti_loss_final_kernel<<<1, 64, 0, stream>>>(ws, out, B);
}

// Round 2
// 10.262 us; speedup vs baseline: 1.1025x; 1.1025x over previous
//
#include <hip/hip_runtime.h>

#define PAD_TOK 0
#define UNK_TOK 1
#define END_TOK 2

// One block; one wave (64 lanes) per batch row. B<=32 assumed (bench: B=16).
// Supports L % 4 == 0, L <= 4096 (bench: L=512).
__global__ __launch_bounds__(1024) void ti_loss_fused_kernel(
    const float* __restrict__ logits,     // [B, L, V]
    const int*   __restrict__ fwd,        // [B, L]
    const int*   __restrict__ tgt,        // [B, L]
    const int*   __restrict__ seqlen,     // [B]
    const int*   __restrict__ inserted,   // [B]
    float*       __restrict__ out,        // [1]
    int B, int L, int V)
{
    const int t    = threadIdx.x;
    const int wid  = t >> 6;
    const int lane = t & 63;
    const int nw   = blockDim.x >> 6;

    __shared__ float s_val[32];
    __shared__ float s_act[32];

    for (int b = wid; b < B; b += nw) {
        const int*   frow = fwd + (size_t)b * L;
        const int*   trow = tgt + (size_t)b * L;
        const float* lrow = logits + (size_t)b * L * V;

        // ---- vectorized load of the fwd row: lane covers [4*lane + k*256, +3] ----
        int4 v[4];                       // up to L=4096
        int niter = 0;
        for (int base = 4 * lane; base < L; base += 256) {
            v[niter++] = *(const int4*)(frow + base);
        }

        // ---- lane-local first-PAD, then wave shuffle-min ----
        int lfp = L;
        for (int k = 0; k < niter; ++k) {
            const int base = 4 * lane + k * 256;
            if (v[k].x == PAD_TOK) lfp = min(lfp, base + 0);
            if (v[k].y == PAD_TOK) lfp = min(lfp, base + 1);
            if (v[k].z == PAD_TOK) lfp = min(lfp, base + 2);
            if (v[k].w == PAD_TOK) lfp = min(lfp, base + 3);
        }
        #pragma unroll
        for (int off = 32; off > 0; off >>= 1)
            lfp = min(lfp, __shfl_xor(lfp, off));
        const int fp = lfp;

        // ---- gather -log(p) at UNK positions strictly before first PAD ----
        float sum = 0.f, cnt = 0.f;
        for (int k = 0; k < niter; ++k) {
            const int base = 4 * lane + k * 256;
            const int vals[4] = { v[k].x, v[k].y, v[k].z, v[k].w };
            #pragma unroll
            for (int j = 0; j < 4; ++j) {
                const int i = base + j;
                if (i < fp && vals[j] == UNK_TOK) {
                    const int pt = (i == 0) ? trow[L - 1] : trow[i - 1]; // roll(targets,1)
                    sum -= logf(lrow[(size_t)i * V + pt]);
                    cnt += 1.f;
                }
            }
        }
        #pragma unroll
        for (int off = 32; off > 0; off >>= 1) {
            sum += __shfl_xor(sum, off);
            cnt += __shfl_xor(cnt, off);
        }

        if (lane == 0) {
            float sent;
            if (cnt > 0.f) {
                sent = sum / cnt;  // cnt >= 1 here, so max(cnt,1) == cnt
            } else {
                const int sl = seqlen[b];
                sent = -logf(lrow[(size_t)(sl + 2) * V + END_TOK]);
            }
            const float act = (inserted[b] < seqlen[b]) ? 1.f : 0.f;
            s_val[b] = sent * act;
            s_act[b] = act;
        }
    }
    __syncthreads();

    if (t == 0) {
        float s = 0.f, a = 0.f;
        for (int b = 0; b < B; ++b) { s += s_val[b]; a += s_act[b]; }
        out[0] = s / fmaxf(a, 1.f);
    }
}

extern "C" void kernel_launch(void* const* d_in, const int* in_sizes, int n_in,
                              void* d_out, int out_size, void* d_ws, size_t ws_size,
                              hipStream_t stream) {
    const float* logits   = (const float*)d_in[0];
    const int*   fwd      = (const int*)d_in[1];
    const int*   tgt      = (const int*)d_in[2];
    const int*   seqlen   = (const int*)d_in[3];
    const int*   inserted = (const int*)d_in[4];
    float* out = (float*)d_out;

    const int B = in_sizes[3];              // 16
    const int L = in_sizes[1] / B;          // 512
    const int V = in_sizes[0] / (B * L);    // 32000

    const int waves   = (B < 16) ? B : 16;  // one wave per row, cap at 1024 threads
    const int threads = 64 * waves;

    ti_loss_fused_kernel<<<1, threads, 0, stream>>>(
        logits, fwd, tgt, seqlen, inserted, out, B, L, V);
}

// Round 3
// 9.739 us; speedup vs baseline: 1.1617x; 1.0537x over previous
//
#include <hip/hip_runtime.h>

#define PAD_TOK 0
#define UNK_TOK 1
#define END_TOK 2

// One block; one wave (64 lanes) per batch row (rows strided if B>16).
// Template NITER = L/256 so all per-lane arrays are statically indexed.
template<int NITER>
__global__ __launch_bounds__(1024) void ti_loss_fused_tpl(
    const float* __restrict__ logits,     // [B, L, V]
    const int*   __restrict__ fwd,        // [B, L]
    const int*   __restrict__ tgt,        // [B, L]
    const int*   __restrict__ seqlen,     // [B]
    const int*   __restrict__ inserted,   // [B]
    float*       __restrict__ out,        // [1]
    int B, int V)
{
    constexpr int L = NITER * 256;
    const int t    = threadIdx.x;
    const int wid  = t >> 6;
    const int lane = t & 63;
    const int nw   = blockDim.x >> 6;

    __shared__ float s_val[64];
    __shared__ float s_act[64];

    for (int b = wid; b < B; b += nw) {
        const int*   frow = fwd + (size_t)b * L;
        const int*   trow = tgt + (size_t)b * L;
        const float* lrow = logits + (size_t)b * L * V;

        // Uniform scalar loads hoisted to the top (overlap with row loads).
        const int sl  = seqlen[b];
        const int ins = inserted[b];
        // Speculative fallback gather — always issued, used only if cnt==0.
        const float fbp = lrow[(size_t)(sl + 2) * V + END_TOK];

        // Load fwd row and tgt row concurrently (latencies overlap).
        int4 fv[NITER], tv[NITER];
        #pragma unroll
        for (int k = 0; k < NITER; ++k) {
            fv[k] = *(const int4*)(frow + 4 * lane + k * 256);
            tv[k] = *(const int4*)(trow + 4 * lane + k * 256);
        }

        // prev-target (roll by 1, incl. i==0 wrap to tgt[L-1]) via in-wave shuffles.
        int pt[NITER][4];
        #pragma unroll
        for (int k = 0; k < NITER; ++k) {
            const int kprev  = (k == 0) ? (NITER - 1) : (k - 1);
            const int up_w   = __shfl_up(tv[k].w, 1);        // lane-1's tgt[4(lane-1)+3]
            const int wrap_w = __shfl(tv[kprev].w, 63);      // tgt[k*256-1] (or tgt[L-1])
            pt[k][0] = (lane == 0) ? wrap_w : up_w;
            pt[k][1] = tv[k].x;
            pt[k][2] = tv[k].y;
            pt[k][3] = tv[k].z;
        }

        int fvals[NITER][4];
        #pragma unroll
        for (int k = 0; k < NITER; ++k) {
            fvals[k][0] = fv[k].x; fvals[k][1] = fv[k].y;
            fvals[k][2] = fv[k].z; fvals[k][3] = fv[k].w;
        }

        // Speculative logits gathers at ALL UNK positions (no fp dependency);
        // the i<fp mask is applied at accumulation time.
        float pv[NITER][4];
        #pragma unroll
        for (int k = 0; k < NITER; ++k) {
            #pragma unroll
            for (int j = 0; j < 4; ++j) {
                const int i = 4 * lane + k * 256 + j;
                pv[k][j] = (fvals[k][j] == UNK_TOK)
                         ? lrow[(size_t)i * V + pt[k][j]] : 1.0f;
            }
        }

        // first-PAD position (wave shuffle-min) — overlaps with gather latency.
        int lfp = L;
        #pragma unroll
        for (int k = 0; k < NITER; ++k) {
            #pragma unroll
            for (int j = 0; j < 4; ++j) {
                const int i = 4 * lane + k * 256 + j;
                if (fvals[k][j] == PAD_TOK) lfp = min(lfp, i);
            }
        }
        #pragma unroll
        for (int off = 32; off > 0; off >>= 1)
            lfp = min(lfp, __shfl_xor(lfp, off));
        const int fp = lfp;

        // Masked accumulation.
        float sum = 0.f, cnt = 0.f;
        #pragma unroll
        for (int k = 0; k < NITER; ++k) {
            #pragma unroll
            for (int j = 0; j < 4; ++j) {
                const int i = 4 * lane + k * 256 + j;
                if (i < fp && fvals[k][j] == UNK_TOK) {
                    sum -= logf(pv[k][j]);
                    cnt += 1.f;
                }
            }
        }
        #pragma unroll
        for (int off = 32; off > 0; off >>= 1) {
            sum += __shfl_xor(sum, off);
            cnt += __shfl_xor(cnt, off);
        }

        if (lane == 0) {
            const float sent = (cnt > 0.f) ? (sum / cnt) : -logf(fbp);
            const float act  = (ins < sl) ? 1.f : 0.f;
            s_val[b] = sent * act;
            s_act[b] = act;
        }
    }
    __syncthreads();

    // Wave-0 shuffle reduce over rows (B <= 64).
    if (t < 64) {
        float v_ = (lane < B) ? s_val[lane] : 0.f;
        float a_ = (lane < B) ? s_act[lane] : 0.f;
        #pragma unroll
        for (int off = 32; off > 0; off >>= 1) {
            v_ += __shfl_xor(v_, off);
            a_ += __shfl_xor(a_, off);
        }
        if (lane == 0) out[0] = v_ / fmaxf(a_, 1.f);
    }
}

// Generic fallback for shapes the template doesn't cover (not used at L=512).
__global__ __launch_bounds__(1024) void ti_loss_fused_gen(
    const float* __restrict__ logits, const int* __restrict__ fwd,
    const int* __restrict__ tgt, const int* __restrict__ seqlen,
    const int* __restrict__ inserted, float* __restrict__ out,
    int B, int L, int V)
{
    const int t = threadIdx.x, wid = t >> 6, lane = t & 63, nw = blockDim.x >> 6;
    __shared__ float s_val[64];
    __shared__ float s_act[64];
    for (int b = wid; b < B; b += nw) {
        const int* frow = fwd + (size_t)b * L;
        const int* trow = tgt + (size_t)b * L;
        const float* lrow = logits + (size_t)b * L * V;
        int lfp = L;
        for (int i = lane; i < L; i += 64)
            if (frow[i] == PAD_TOK) lfp = min(lfp, i);
        #pragma unroll
        for (int off = 32; off > 0; off >>= 1) lfp = min(lfp, __shfl_xor(lfp, off));
        const int fp = lfp;
        float sum = 0.f, cnt = 0.f;
        for (int i = lane; i < L; i += 64) {
            if (i < fp && frow[i] == UNK_TOK) {
                const int ptg = (i == 0) ? trow[L - 1] : trow[i - 1];
                sum -= logf(lrow[(size_t)i * V + ptg]);
                cnt += 1.f;
            }
        }
        #pragma unroll
        for (int off = 32; off > 0; off >>= 1) {
            sum += __shfl_xor(sum, off); cnt += __shfl_xor(cnt, off);
        }
        if (lane == 0) {
            float sent = (cnt > 0.f) ? (sum / cnt)
                                     : -logf(lrow[(size_t)(seqlen[b] + 2) * V + END_TOK]);
            const float act = (inserted[b] < seqlen[b]) ? 1.f : 0.f;
            s_val[b] = sent * act; s_act[b] = act;
        }
    }
    __syncthreads();
    if (t < 64) {
        float v_ = (lane < B) ? s_val[lane] : 0.f;
        float a_ = (lane < B) ? s_act[lane] : 0.f;
        #pragma unroll
        for (int off = 32; off > 0; off >>= 1) {
            v_ += __shfl_xor(v_, off); a_ += __shfl_xor(a_, off);
        }
        if (lane == 0) out[0] = v_ / fmaxf(a_, 1.f);
    }
}

extern "C" void kernel_launch(void* const* d_in, const int* in_sizes, int n_in,
                              void* d_out, int out_size, void* d_ws, size_t ws_size,
                              hipStream_t stream) {
    const float* logits   = (const float*)d_in[0];
    const int*   fwd      = (const int*)d_in[1];
    const int*   tgt      = (const int*)d_in[2];
    const int*   seqlen   = (const int*)d_in[3];
    const int*   inserted = (const int*)d_in[4];
    float* out = (float*)d_out;

    const int B = in_sizes[3];              // 16
    const int L = in_sizes[1] / B;          // 512
    const int V = in_sizes[0] / (B * L);    // 32000

    const int waves   = (B < 16) ? B : 16;
    const int threads = 64 * waves;

    if (L == 512) {
        ti_loss_fused_tpl<2><<<1, threads, 0, stream>>>(
            logits, fwd, tgt, seqlen, inserted, out, B, V);
    } else if (L == 256) {
        ti_loss_fused_tpl<1><<<1, threads, 0, stream>>>(
            logits, fwd, tgt, seqlen, inserted, out, B, V);
    } else if (L == 1024) {
        ti_loss_fused_tpl<4><<<1, threads, 0, stream>>>(
            logits, fwd, tgt, seqlen, inserted, out, B, V);
    } else {
        ti_loss_fused_gen<<<1, threads, 0, stream>>>(
            logits, fwd, tgt, seqlen, inserted, out, B, L, V);
    }
}

// Round 4
// 9.684 us; speedup vs baseline: 1.1683x; 1.0057x over previous
//
#include <hip/hip_runtime.h>

#define PAD_TOK 0
#define UNK_TOK 1
#define END_TOK 2

#define LN2F 0.6931471805599453f

// One block; one wave (64 lanes) per batch row (rows strided if B>16).
// Template NITER = L/256 so all per-lane arrays are statically indexed.
template<int NITER>
__global__ __launch_bounds__(1024) void ti_loss_fused_tpl(
    const float* __restrict__ logits,     // [B, L, V]
    const int*   __restrict__ fwd,        // [B, L]
    const int*   __restrict__ tgt,        // [B, L]
    const int*   __restrict__ seqlen,     // [B]
    const int*   __restrict__ inserted,   // [B]
    float*       __restrict__ out,        // [1]
    int B, int V)
{
    constexpr int L = NITER * 256;
    const int t    = threadIdx.x;
    const int wid  = t >> 6;
    const int lane = t & 63;
    const int nw   = blockDim.x >> 6;

    __shared__ float s_val[64];
    __shared__ float s_act[64];

    for (int b = wid; b < B; b += nw) {
        const int*   frow = fwd + (size_t)b * L;
        const int*   trow = tgt + (size_t)b * L;
        const float* lrow = logits + (size_t)b * L * V;

        // Uniform scalar loads hoisted to the top (overlap with row loads).
        const int sl  = seqlen[b];
        const int ins = inserted[b];
        // Speculative fallback gather — always issued, used only if cnt==0.
        const float fbp = lrow[(unsigned)(sl + 2) * (unsigned)V + END_TOK];

        // Load fwd row and tgt row concurrently (latencies overlap).
        int4 fv[NITER], tv[NITER];
        #pragma unroll
        for (int k = 0; k < NITER; ++k) {
            fv[k] = *(const int4*)(frow + 4 * lane + k * 256);
            tv[k] = *(const int4*)(trow + 4 * lane + k * 256);
        }

        // prev-target (roll by 1, incl. i==0 wrap to tgt[L-1]) via in-wave shuffles.
        int pt[NITER][4];
        #pragma unroll
        for (int k = 0; k < NITER; ++k) {
            const int kprev  = (k == 0) ? (NITER - 1) : (k - 1);
            const int up_w   = __shfl_up(tv[k].w, 1);        // lane-1's tgt[4(lane-1)+3]
            const int wrap_w = __shfl(tv[kprev].w, 63);      // tgt[k*256-1] (or tgt[L-1])
            pt[k][0] = (lane == 0) ? wrap_w : up_w;
            pt[k][1] = tv[k].x;
            pt[k][2] = tv[k].y;
            pt[k][3] = tv[k].z;
        }

        int fvals[NITER][4];
        #pragma unroll
        for (int k = 0; k < NITER; ++k) {
            fvals[k][0] = fv[k].x; fvals[k][1] = fv[k].y;
            fvals[k][2] = fv[k].z; fvals[k][3] = fv[k].w;
        }

        // Speculative logits gathers at ALL UNK positions (no fp dependency);
        // 32-bit offsets: base = 4*lane*V (once), slot constant (k*256+j)*V folded.
        const unsigned baseoff = (unsigned)(4 * lane) * (unsigned)V;
        float pv[NITER][4];
        #pragma unroll
        for (int k = 0; k < NITER; ++k) {
            #pragma unroll
            for (int j = 0; j < 4; ++j) {
                const unsigned off = baseoff + (unsigned)((k * 256 + j)) * (unsigned)V
                                   + (unsigned)pt[k][j];
                pv[k][j] = (fvals[k][j] == UNK_TOK) ? lrow[off] : 1.0f;
            }
        }

        // first-PAD position (wave shuffle-min) — overlaps with gather latency.
        int lfp = L;
        #pragma unroll
        for (int k = 0; k < NITER; ++k) {
            #pragma unroll
            for (int j = 0; j < 4; ++j) {
                const int i = 4 * lane + k * 256 + j;
                if (fvals[k][j] == PAD_TOK) lfp = min(lfp, i);
            }
        }
        #pragma unroll
        for (int off = 32; off > 0; off >>= 1)
            lfp = min(lfp, __shfl_xor(lfp, off));
        const int fp = lfp;

        // Masked accumulation in log2 domain (single v_log_f32 per slot).
        float sum2 = 0.f, cnt = 0.f;
        #pragma unroll
        for (int k = 0; k < NITER; ++k) {
            #pragma unroll
            for (int j = 0; j < 4; ++j) {
                const int i = 4 * lane + k * 256 + j;
                if (i < fp && fvals[k][j] == UNK_TOK) {
                    sum2 -= __log2f(pv[k][j]);
                    cnt  += 1.f;
                }
            }
        }
        #pragma unroll
        for (int off = 32; off > 0; off >>= 1) {
            sum2 += __shfl_xor(sum2, off);
            cnt  += __shfl_xor(cnt, off);
        }

        if (lane == 0) {
            const float sent2 = (cnt > 0.f) ? (sum2 / cnt) : -__log2f(fbp);
            const float act   = (ins < sl) ? 1.f : 0.f;
            s_val[b] = sent2 * LN2F * act;
            s_act[b] = act;
        }
    }
    __syncthreads();

    // Wave-0 shuffle reduce over rows (B <= 64).
    if (t < 64) {
        float v_ = (lane < B) ? s_val[lane] : 0.f;
        float a_ = (lane < B) ? s_act[lane] : 0.f;
        #pragma unroll
        for (int off = 32; off > 0; off >>= 1) {
            v_ += __shfl_xor(v_, off);
            a_ += __shfl_xor(a_, off);
        }
        if (lane == 0) out[0] = v_ / fmaxf(a_, 1.f);
    }
}

// Generic fallback for shapes the template doesn't cover (not used at L=512).
__global__ __launch_bounds__(1024) void ti_loss_fused_gen(
    const float* __restrict__ logits, const int* __restrict__ fwd,
    const int* __restrict__ tgt, const int* __restrict__ seqlen,
    const int* __restrict__ inserted, float* __restrict__ out,
    int B, int L, int V)
{
    const int t = threadIdx.x, wid = t >> 6, lane = t & 63, nw = blockDim.x >> 6;
    __shared__ float s_val[64];
    __shared__ float s_act[64];
    for (int b = wid; b < B; b += nw) {
        const int* frow = fwd + (size_t)b * L;
        const int* trow = tgt + (size_t)b * L;
        const float* lrow = logits + (size_t)b * L * V;
        int lfp = L;
        for (int i = lane; i < L; i += 64)
            if (frow[i] == PAD_TOK) lfp = min(lfp, i);
        #pragma unroll
        for (int off = 32; off > 0; off >>= 1) lfp = min(lfp, __shfl_xor(lfp, off));
        const int fp = lfp;
        float sum = 0.f, cnt = 0.f;
        for (int i = lane; i < L; i += 64) {
            if (i < fp && frow[i] == UNK_TOK) {
                const int ptg = (i == 0) ? trow[L - 1] : trow[i - 1];
                sum -= logf(lrow[(size_t)i * V + ptg]);
                cnt += 1.f;
            }
        }
        #pragma unroll
        for (int off = 32; off > 0; off >>= 1) {
            sum += __shfl_xor(sum, off); cnt += __shfl_xor(cnt, off);
        }
        if (lane == 0) {
            float sent = (cnt > 0.f) ? (sum / cnt)
                                     : -logf(lrow[(size_t)(seqlen[b] + 2) * V + END_TOK]);
            const float act = (inserted[b] < seqlen[b]) ? 1.f : 0.f;
            s_val[b] = sent * act; s_act[b] = act;
        }
    }
    __syncthreads();
    if (t < 64) {
        float v_ = (lane < B) ? s_val[lane] : 0.f;
        float a_ = (lane < B) ? s_act[lane] : 0.f;
        #pragma unroll
        for (int off = 32; off > 0; off >>= 1) {
            v_ += __shfl_xor(v_, off); a_ += __shfl_xor(a_, off);
        }
        if (lane == 0) out[0] = v_ / fmaxf(a_, 1.f);
    }
}

extern "C" void kernel_launch(void* const* d_in, const int* in_sizes, int n_in,
                              void* d_out, int out_size, void* d_ws, size_t ws_size,
                              hipStream_t stream) {
    const float* logits   = (const float*)d_in[0];
    const int*   fwd      = (const int*)d_in[1];
    const int*   tgt      = (const int*)d_in[2];
    const int*   seqlen   = (const int*)d_in[3];
    const int*   inserted = (const int*)d_in[4];
    float* out = (float*)d_out;

    const int B = in_sizes[3];              // 16
    const int L = in_sizes[1] / B;          // 512
    const int V = in_sizes[0] / (B * L);    // 32000

    const int waves   = (B < 16) ? B : 16;
    const int threads = 64 * waves;

    if (L == 512) {
        ti_loss_fused_tpl<2><<<1, threads, 0, stream>>>(
            logits, fwd, tgt, seqlen, inserted, out, B, V);
    } else if (L == 256) {
        ti_loss_fused_tpl<1><<<1, threads, 0, stream>>>(
            logits, fwd, tgt, seqlen, inserted, out, B, V);
    } else if (L == 1024) {
        ti_loss_fused_tpl<4><<<1, threads, 0, stream>>>(
            logits, fwd, tgt, seqlen, inserted, out, B, V);
    } else {
        ti_loss_fused_gen<<<1, threads, 0, stream>>>(
            logits, fwd, tgt, seqlen, inserted, out, B, L, V);
    }
}